// Round 5
// baseline (58.689 us; speedup 1.0000x reference)
//
#include <hip/hip_runtime.h>

#define NB 8
#define NL 512
#define ND 128

constexpr float CEXP = 2.8853900817779268f;   // 2*log2(e): exp2(CEXP*x) = e^{2x}

typedef float v2f __attribute__((ext_vector_type(2)));

// wpack: transpose+d4-pack weights (wp[(d>>2)*512 + e*4 + (d&3)] = w[e][d])
// so qk's weight loads are lane-coalesced.
__global__ __launch_bounds__(256) void wpack_kernel(
    const float* __restrict__ uw, const float* __restrict__ vw,
    float* __restrict__ uwp, float* __restrict__ vwp) {
  const int m = blockIdx.x >> 4;                        // 0: uw, 1: vw
  const int t = (blockIdx.x & 15) * 256 + threadIdx.x;  // 0..4095
  const float4* src = (const float4*)(m ? vw : uw);
  float4* dst = (float4*)(m ? vwp : uwp);
  const int e = t >> 5, d4 = t & 31;
  float4 v = src[e * 32 + d4];       // w[e][4d4..+3], coalesced read
  dst[d4 * 128 + e] = v;             // wp[d4][e][4]
}

// Kernel A: q = inp @ uw^T, k = inp @ vw^T.
//  eqp = exp2(CEXP*q), d4-packed-transposed [b][e4][l][4]  (VMEM stream)
//  ekq = exp2(CEXP*k), slot-interleaved [b][tile][e][8] with slot order
//        (i0,i4,i1,i5,i2,i6,i3,i7) so attn reads aligned v2f pairs.
// inp rows are read via uniform s_loads (no LDS staging, no barrier).
__global__ __launch_bounds__(256) void qk_kernel(
    const float* __restrict__ inp, const float* __restrict__ uwp,
    const float* __restrict__ vwp, float* __restrict__ eqp,
    float* __restrict__ ekq) {
  __shared__ float qt[128][9];    // pad 9: conflict-free transpose
  const int b = blockIdx.x & 7;   // batch-per-XCD affinity (matches attn)
  const int l0 = (blockIdx.x >> 3) * 8;
  const int tid = threadIdx.x;

  const int e = tid & 127;
  const int half = tid >> 7;                 // 0 -> q (uw), 1 -> k (vw)
  const float* xrow = inp + (b * NL + l0) * ND;   // uniform base -> s_load
  const float4* W4 = (const float4*)(half ? vwp : uwp) + e;  // coalesced
  float acc[8];
#pragma unroll
  for (int r = 0; r < 8; ++r) acc[r] = 0.f;
  float4 w = W4[0];
  for (int d4 = 0; d4 < 32; ++d4) {
    float4 wn = W4[(size_t)((d4 + 1 > 31) ? 31 : d4 + 1) * 128];
#pragma unroll
    for (int r = 0; r < 8; ++r) {
      // uniform address -> scalar loads, broadcast as SGPR operands
      float4 x = *((const float4*)&xrow[r * ND + 4 * d4]);
      acc[r] = fmaf(w.x, x.x, acc[r]);
      acc[r] = fmaf(w.y, x.y, acc[r]);
      acc[r] = fmaf(w.z, x.z, acc[r]);
      acc[r] = fmaf(w.w, x.w, acc[r]);
    }
    w = wn;
  }
  if (half) {
    float* ekb = ekq + ((size_t)(b * 64 + (l0 >> 3)) * 128 + e) * 8;
#pragma unroll
    for (int r = 0; r < 8; ++r) {
      const int slot = (r & 3) * 2 + (r >> 2);
      ekb[slot] = __builtin_amdgcn_exp2f(CEXP * acc[r]);  // 32B/thread
    }
  } else {
#pragma unroll
    for (int r = 0; r < 8; ++r)
      qt[e][r] = __builtin_amdgcn_exp2f(CEXP * acc[r]);
  }
  __syncthreads();
  {
    // all 256 threads: thread -> (e4 = tid>>3, r = tid&7)
    const int e4 = tid >> 3, r = tid & 7;
    float4 v = make_float4(qt[4 * e4][r], qt[4 * e4 + 1][r],
                           qt[4 * e4 + 2][r], qt[4 * e4 + 3][r]);
    ((float4*)eqp)[(b * 32 + e4) * NL + l0 + r] = v;
  }
}

// Kernel B: 8-row i-tile, 512 threads, 512 blocks — the round-0 winner
// (39.3us) with ONE surgical change: the uniform ek/aw streams move from
// scalar-memory (s_load/K$) into LDS, staged once per block.
// Evidence: dur*VALUBusy is conserved across 2/4/8-wave-per-SIMD variants
// (R0 20.8, R3 23.6, R4 20.3 us-units) while busy% never exceeds ~53 at
// any residency -> the stall is a SHARED resource, and the prime suspect
// is the K$/scalar-mem path (32B/d-iter/wave of s_load, shared per CU
// cluster, ~1-deep pipelined). LDS broadcast reads (imm-offset ds_read,
// zero addr math, separate 128B/cy pipe) remove that contention; the
// score loop's lgkmcnt then tracks only the in-order LDS stream.
__global__ __launch_bounds__(512, 4) void attn_kernel(
    const float* __restrict__ inp, const float* __restrict__ aw,
    const float* __restrict__ eqp, const float* __restrict__ ekq,
    float* __restrict__ out, float* __restrict__ attn) {
  // ek/aw (score phase) alias the PV partials buffer (PV phase): disjoint
  // lifetimes separated by two barriers.
  __shared__ union ShU {
    v2f red[8][8][64];          // 32KB, PV partials
    float ek[1024 + 128];       // score: ek[d*8+slot] (4KB) + aw at [1024+d]
  } sh;
  __shared__ float attn_lds[8][512];   // 16KB
  __shared__ float rsum[8][8];

  const int b = blockIdx.x & 7;       // batch-per-XCD affinity
  const int i0 = (blockIdx.x >> 3) * 8;
  const int tid = threadIdx.x;
  const int lane = tid & 63;
  const int wid = tid >> 6;

  // ---- stage ek tile (1024 floats) + aw (128 floats) into LDS
  {
    const v2f* ekg = (const v2f*)(ekq + (size_t)(b * 64 + (i0 >> 3)) * 128 * 8);
    ((v2f*)sh.ek)[tid] = ekg[tid];               // coalesced 4KB
    if (tid < 128) sh.ek[1024 + tid] = aw[tid];  // 512B
  }
  __syncthreads();

  // ---- score stage: thread owns column j = tid; 8 rows as 4 v2f pairs
  v2f acc04 = {0.f, 0.f}, acc15 = {0.f, 0.f};
  v2f acc26 = {0.f, 0.f}, acc37 = {0.f, 0.f};
  const v2f ONE2 = {1.f, 1.f};
  const float4* eq4 = (const float4*)eqp + (size_t)(b * 32) * NL + tid;
  const v2f* ekL = (const v2f*)sh.ek;     // LDS broadcast, imm offsets
  const float* awL = sh.ek + 1024;
  float4 eA = eq4[0];
  float4 eB = eq4[NL];
#pragma unroll 4
  for (int d4 = 0; d4 < 32; ++d4) {
    const int nf = (d4 + 2 > 31) ? 31 : d4 + 2;      // 2-deep prefetch
    float4 eC = eq4[(size_t)nf * NL];
#pragma unroll
    for (int dd = 0; dd < 4; ++dd) {
      const int d = 4 * d4 + dd;
      const float eqs = (dd == 0) ? eA.x : (dd == 1) ? eA.y
                       : (dd == 2) ? eA.z : eA.w;
      const float na = awL[d];     // ds_read_b32, imm offset
      v2f e01 = ekL[d * 4 + 0];    // ds_read, uniform addr -> broadcast
      v2f e23 = ekL[d * 4 + 1];
      v2f e45 = ekL[d * 4 + 2];
      v2f e67 = ekL[d * 4 + 3];
      v2f eq2 = {eqs, eqs};
      // p = 1 + eq*ek; tanh = 1 - 2/p; "+1" terms softmax-invariant,
      // the -2 is folded into the exp2 constant below.
      v2f Pa = __builtin_elementwise_fma(eq2, e01, ONE2);  // rows (0,4)
      v2f Pb = __builtin_elementwise_fma(eq2, e23, ONE2);  // rows (1,5)
      v2f Pc = __builtin_elementwise_fma(eq2, e45, ONE2);  // rows (2,6)
      v2f Pd = __builtin_elementwise_fma(eq2, e67, ONE2);  // rows (3,7)
      v2f M1 = Pa * Pb;    // (p0p1, p4p5)
      v2f M2 = Pc * Pd;    // (p2p3, p6p7)
      v2f Q = M1 * M2;     // (p0123, p4567)
      v2f NR = {na * __builtin_amdgcn_rcpf(Q.x),
                na * __builtin_amdgcn_rcpf(Q.y)};
      v2f T = NR * M2;     // (na/p01, na/p45)
      v2f U = NR * M1;     // (na/p23, na/p67)
      acc04 = __builtin_elementwise_fma(T, Pb, acc04);   // na/p0, na/p4
      acc15 = __builtin_elementwise_fma(T, Pa, acc15);
      acc26 = __builtin_elementwise_fma(U, Pd, acc26);
      acc37 = __builtin_elementwise_fma(U, Pc, acc37);
    }
    eA = eB;
    eB = eC;
  }
  float acc[8] = {acc04.x, acc15.x, acc26.x, acc37.x,
                  acc04.y, acc15.y, acc26.y, acc37.y};

  // ---- softmax over j; score = -2*acc (fold -2 into exp2 constant);
  // no max-subtraction: |exp2 arg| <= ~26, safe in f32.
  float sinv[8], ex[8];
#pragma unroll
  for (int i = 0; i < 8; ++i) {
    float e = __builtin_amdgcn_exp2f(acc[i] * (-CEXP));
    ex[i] = e;
    float s = e;
#pragma unroll
    for (int off = 32; off; off >>= 1) s += __shfl_xor(s, off);
    if (lane == 0) rsum[wid][i] = s;
  }
  __syncthreads();
#pragma unroll
  for (int i = 0; i < 8; ++i) {
    float s = ((rsum[0][i] + rsum[1][i]) + (rsum[2][i] + rsum[3][i])) +
              ((rsum[4][i] + rsum[5][i]) + (rsum[6][i] + rsum[7][i]));
    sinv[i] = __builtin_amdgcn_rcpf(s);
  }

  float* attnb = attn + (size_t)(b * NL + i0) * NL;
#pragma unroll
  for (int i = 0; i < 8; ++i) {
    float a = ex[i] * sinv[i];
    attn_lds[i][tid] = a;
    attnb[i * NL + tid] = a;           // coalesced
  }
  __syncthreads();     // also fences last sh.ek reads before red reuse

  // ---- PV: wave w owns j in [64w, 64w+64); lane owns v2f d-pair
  v2f po[8];
#pragma unroll
  for (int i = 0; i < 8; ++i) po[i] = (v2f){0.f, 0.f};
  const v2f* inp2 = (const v2f*)(inp + b * NL * ND);
  for (int jj4 = 0; jj4 < 16; ++jj4) {
    const int jc = wid * 64 + jj4 * 4;
    v2f x0 = inp2[(jc + 0) * 64 + lane];   // coalesced (L2-resident)
    v2f x1 = inp2[(jc + 1) * 64 + lane];
    v2f x2 = inp2[(jc + 2) * 64 + lane];
    v2f x3 = inp2[(jc + 3) * 64 + lane];
#pragma unroll
    for (int i = 0; i < 8; ++i) {
      float4 a4 = *((const float4*)&attn_lds[i][jc]);   // uniform broadcast
      po[i] = __builtin_elementwise_fma((v2f){a4.x, a4.x}, x0, po[i]);
      po[i] = __builtin_elementwise_fma((v2f){a4.y, a4.y}, x1, po[i]);
      po[i] = __builtin_elementwise_fma((v2f){a4.z, a4.z}, x2, po[i]);
      po[i] = __builtin_elementwise_fma((v2f){a4.w, a4.w}, x3, po[i]);
    }
  }
#pragma unroll
  for (int i = 0; i < 8; ++i) sh.red[wid][i][lane] = po[i];
  __syncthreads();
  {
    const int i2 = wid, dl = lane;
    v2f s = sh.red[0][i2][dl];
#pragma unroll
    for (int p = 1; p < 8; ++p) s += sh.red[p][i2][dl];
    *(v2f*)&out[(size_t)(b * NL + i0 + i2) * ND + dl * 2] = s;
  }
}

extern "C" void kernel_launch(void* const* d_in, const int* in_sizes, int n_in,
                              void* d_out, int out_size, void* d_ws,
                              size_t ws_size, hipStream_t stream) {
  const float* inp = (const float*)d_in[0];
  const float* uw = (const float*)d_in[1];
  const float* vw = (const float*)d_in[2];
  const float* aw = (const float*)d_in[3];
  float* out = (float*)d_out;
  float* attn = out + NB * NL * ND;        // tuple order: (out, attn)
  float* eqp = (float*)d_ws;               // [B][32][512][4] packed exp2 q
  float* ekq = eqp + NB * ND * NL;         // [B][64][128][8] slot-interleaved
  size_t need = (size_t)2 * NB * ND * NL * 4 + 32768 * 4;
  float* wp = (ws_size >= need) ? (ekq + NB * ND * NL) : (attn);
  float* uwp = wp;                 // 16384
  float* vwp = wp + 16384;         // 16384
  wpack_kernel<<<dim3(32), 256, 0, stream>>>(uw, vw, uwp, vwp);
  qk_kernel<<<dim3(NB * 64), 256, 0, stream>>>(inp, uwp, vwp, eqp, ekq);
  attn_kernel<<<dim3(NB * 64), 512, 0, stream>>>(inp, aw, eqp, ekq, out, attn);
}